// Round 6
// baseline (1210.401 us; speedup 1.0000x reference)
//
#include <hip/hip_runtime.h>
#include <hip/hip_bf16.h>

typedef __attribute__((ext_vector_type(8))) short short8v;
typedef __attribute__((ext_vector_type(4))) float f32x4;
typedef __hip_bfloat16 bf16;

#define BDIM 512
#define NHEADS 8
#define DK 64
#define NBATCH 256
#define NN3 256
#define NN4 64
#define NMLP 2048

#define GLOAD_LDS16(g, l)                                                  \
  __builtin_amdgcn_global_load_lds(                                        \
      (const __attribute__((address_space(1))) void*)(g),                  \
      (__attribute__((address_space(3))) void*)(l), 16, 0, 0)

__device__ __forceinline__ float bf2f(short s) {
  union { short u[2]; float f; } cv;
  cv.u[0] = 0; cv.u[1] = s;
  return cv.f;
}
__device__ __forceinline__ short f2bf(float x) {
  bf16 h = __float2bfloat16(x);
  return *reinterpret_cast<short*>(&h);
}

// ---------------- weight convert: Wt[n][k] = bf16(W[k][n]) ----------------
__global__ __launch_bounds__(256) void convert_wt_kernel(
    const float* __restrict__ W, bf16* __restrict__ Wt, int K, int N) {
  int idx = blockIdx.x * 256 + threadIdx.x;
  if (idx >= K * N) return;
  int n = idx / K;
  int k = idx - n * K;
  Wt[idx] = __float2bfloat16(W[(size_t)k * N + n]);
}

// -------- W1 convert with ln3_g fold: W1gt[n][k] = bf16(g[k]*W1[k][n]) ----
__global__ __launch_bounds__(256) void convert_w1g_kernel(
    const float* __restrict__ W, const float* __restrict__ g,
    bf16* __restrict__ Wt) {
  int idx = blockIdx.x * 256 + threadIdx.x;
  if (idx >= BDIM * NMLP) return;
  int n = idx / BDIM;
  int k = idx - n * BDIM;
  Wt[idx] = __float2bfloat16(g[k] * W[(size_t)k * NMLP + n]);
}

// -------- b1 fold: b1p[n] = b1[n] + sum_k ln3_b[k] * W1[k][n] -------------
__global__ __launch_bounds__(256) void b1fold_kernel(
    const float* __restrict__ W1, const float* __restrict__ b1,
    const float* __restrict__ lnb, float* __restrict__ b1p) {
  int n = blockIdx.x * 256 + threadIdx.x;
  if (n >= NMLP) return;
  float s = b1[n];
  for (int k = 0; k < BDIM; k++) s += lnb[k] * W1[(size_t)k * NMLP + n];
  b1p[n] = s;
}

// ---------------- LayerNorm over 512, optional +pos, optional raw out ------
__global__ __launch_bounds__(256) void ln_kernel(
    const float* __restrict__ x, const float* __restrict__ g,
    const float* __restrict__ beta, const float* __restrict__ pos, int nmod,
    bf16* __restrict__ out1, bf16* __restrict__ out2) {
  int row = blockIdx.x;
  int t = threadIdx.x;
  const float* xr = x + (size_t)row * BDIM;
  float2 v = *(const float2*)(xr + t * 2);
  float s = v.x + v.y;
  float sq = v.x * v.x + v.y * v.y;
  for (int o = 32; o > 0; o >>= 1) {
    s += __shfl_down(s, o);
    sq += __shfl_down(sq, o);
  }
  __shared__ float ls[4], lq[4];
  int w = t >> 6;
  if ((t & 63) == 0) { ls[w] = s; lq[w] = sq; }
  __syncthreads();
  s = ls[0] + ls[1] + ls[2] + ls[3];
  sq = lq[0] + lq[1] + lq[2] + lq[3];
  float mean = s * (1.f / BDIM);
  float var = sq * (1.f / BDIM) - mean * mean;
  float rstd = rsqrtf(var + 1e-5f);
  int n = row % nmod;
  for (int i = 0; i < 2; i++) {
    int c = t * 2 + i;
    float xv = i ? v.y : v.x;
    float nv = (xv - mean) * rstd * g[c] + beta[c];
    if (out2) out2[(size_t)row * BDIM + c] = __float2bfloat16(nv);
    float o1 = nv + (pos ? pos[(size_t)n * BDIM + c] : 0.f);
    out1[(size_t)row * BDIM + c] = __float2bfloat16(o1);
  }
}

// ---------------- LDS-staged MFMA GEMM: out[M,N] = X[M,K] @ Wt[N,K]^T -----
// EPI 0: bf16 out = acc + bias
// EPI 3: bf16 out = src(f32) + acc + bias   (residual-in, bf16 out)
template <int EPI>
__global__ __launch_bounds__(256) void gemm_kernel(
    const bf16* __restrict__ X, const bf16* __restrict__ Wt,
    const float* __restrict__ bias, const float* __restrict__ src, void* outp,
    int K, int ldx, int ldw, int N, int gridX) {
  __shared__ __align__(128) bf16 lds[32768];  // 2 buf x (A[128][64]+B[128][64])

  int nwg = gridDim.x;
  int cpx = nwg >> 3;
  int bid = blockIdx.x;
  int nb = (bid & 7) * cpx + (bid >> 3);
  int bx = nb % gridX, by = nb / gridX;
  int row0 = by * 128, col0 = bx * 128;

  int t = threadIdx.x, w = t >> 6, lane = t & 63;
  int wr = w >> 1, wc = w & 1;
  int r16 = lane & 15, kg = lane >> 4;

  int srow = (lane >> 3);
  int scol = ((lane & 7) ^ srow) * 8;
  const bf16* gA0 = X + (size_t)(row0 + w * 32 + srow) * ldx + scol;
  const bf16* gB0 = Wt + (size_t)(col0 + w * 32 + srow) * ldw + scol;

  f32x4 acc[4][4] = {};

  auto stage = [&](int ktel, int buf) {
    bf16* lA = lds + buf * 16384 + w * 32 * 64;
    bf16* lB = lds + buf * 16384 + 8192 + w * 32 * 64;
#pragma unroll
    for (int j = 0; j < 4; j++) {
      GLOAD_LDS16(gA0 + ktel + (size_t)j * 8 * ldx, lA + j * 512);
      GLOAD_LDS16(gB0 + ktel + (size_t)j * 8 * ldw, lB + j * 512);
    }
  };

  auto compute = [&](int buf) {
    const char* base = (const char*)lds + buf * 32768;
#pragma unroll
    for (int ksub = 0; ksub < 2; ksub++) {
      int cc = (ksub * 64 + kg * 16) ^ ((r16 & 7) << 4);
      short8v a[4], b[4];
#pragma unroll
      for (int mi = 0; mi < 4; mi++)
        a[mi] = *(const short8v*)(base + (wr * 64 + mi * 16 + r16) * 128 + cc);
#pragma unroll
      for (int ni = 0; ni < 4; ni++)
        b[ni] = *(const short8v*)(base + 16384 + (wc * 64 + ni * 16 + r16) * 128 + cc);
#pragma unroll
      for (int mi = 0; mi < 4; mi++)
#pragma unroll
        for (int ni = 0; ni < 4; ni++)
          acc[mi][ni] =
              __builtin_amdgcn_mfma_f32_16x16x32_bf16(a[mi], b[ni], acc[mi][ni], 0, 0, 0);
    }
  };

  int NT = K >> 6;
  stage(0, 0);
  __syncthreads();
  int cur = 0;
  for (int kt = 1; kt < NT; kt++) {
    stage(kt << 6, cur ^ 1);
    compute(cur);
    __syncthreads();
    cur ^= 1;
  }
  compute(cur);

#pragma unroll
  for (int ni = 0; ni < 4; ni++) {
    int col = col0 + wc * 64 + ni * 16 + r16;
    float bv = bias ? bias[col] : 0.f;
#pragma unroll
    for (int mi = 0; mi < 4; mi++)
#pragma unroll
      for (int r = 0; r < 4; r++) {
        int row = row0 + wr * 64 + mi * 16 + kg * 4 + r;
        size_t o = (size_t)row * N + col;
        float val = acc[mi][ni][r] + bv;
        if (EPI == 0) {
          ((bf16*)outp)[o] = __float2bfloat16(val);
        } else {
          ((bf16*)outp)[o] = __float2bfloat16(src[o] + val);
        }
      }
  }
}

// ---- ctx: fused k-softmax (over positions) + ctxT[bh][vc][kc] einsum -----
__global__ __launch_bounds__(256) void ctx_kernel(
    const bf16* __restrict__ kproj, const bf16* __restrict__ vbuf,
    bf16* __restrict__ ctxT) {
  int bh = blockIdx.x;
  int b = bh >> 3, h = bh & 7;
  __shared__ bf16 lk[NN4][DK], lv[NN4][DK];
  int t = threadIdx.x;
#pragma unroll
  for (int i = 0; i < 16; i++) {
    int idx = i * 256 + t;
    int n = idx >> 6, c = idx & 63;
    size_t gaddr = (size_t)b * NN4 * BDIM + (size_t)n * BDIM + h * DK + c;
    lk[n][c] = kproj[gaddr];
    lv[n][c] = vbuf[gaddr];
  }
  __syncthreads();
  if (t < 64) {
    int c = t;
    float e[NN4];
    float m = -1e30f;
#pragma unroll
    for (int n = 0; n < NN4; n++) {
      e[n] = bf2f(*(short*)&lk[n][c]);
      m = fmaxf(m, e[n]);
    }
    float s = 0.f;
#pragma unroll
    for (int n = 0; n < NN4; n++) {
      e[n] = __expf(e[n] - m);
      s += e[n];
    }
    float inv = 1.f / s;
#pragma unroll
    for (int n = 0; n < NN4; n++) lk[n][c] = __float2bfloat16(e[n] * inv);
  }
  __syncthreads();
  int vc = t >> 2;
  int kc0 = (t & 3) * 16;
  float acc[16] = {};
  for (int n = 0; n < NN4; n++) {
    float vv = __bfloat162float(lv[n][vc]);
#pragma unroll
    for (int i = 0; i < 16; i++)
      acc[i] += vv * __bfloat162float(lk[n][kc0 + i]);
  }
  size_t o = (size_t)bh * 4096 + (size_t)vc * 64 + kc0;
#pragma unroll
  for (int i = 0; i < 16; i++) ctxT[o + i] = __float2bfloat16(acc[i]);
}

// ---- att: fused q-softmax (in-register, over 64 head channels) + GEMM ----
__global__ __launch_bounds__(256) void att_kernel(
    const bf16* __restrict__ qproj, const bf16* __restrict__ ctxT,
    bf16* __restrict__ att) {
  int bh = blockIdx.x;
  int b = bh >> 3, h = bh & 7;
  int t = threadIdx.x, w = t >> 6, lane = t & 63;
  int r16 = lane & 15, kg = lane >> 4;
  f32x4 acc[4][4] = {};
  const bf16* qb = qproj + (size_t)b * NN3 * BDIM + h * DK;
  const bf16* cb = ctxT + (size_t)bh * 4096;
  short8v bb[2][4];
#pragma unroll
  for (int kt = 0; kt < 2; kt++)
#pragma unroll
    for (int ni = 0; ni < 4; ni++)
      bb[kt][ni] = *(const short8v*)(cb + (ni * 16 + r16) * 64 + kt * 32 + kg * 8);
#pragma unroll
  for (int mi = 0; mi < 4; mi++) {
    int rrow = w * 64 + mi * 16 + r16;
    short8v a0 = *(const short8v*)(qb + (size_t)rrow * BDIM + kg * 8);
    short8v a1 = *(const short8v*)(qb + (size_t)rrow * BDIM + 32 + kg * 8);
    float f[16];
#pragma unroll
    for (int i = 0; i < 8; i++) {
      f[i] = bf2f(a0[i]);
      f[8 + i] = bf2f(a1[i]);
    }
    float m = f[0];
#pragma unroll
    for (int i = 1; i < 16; i++) m = fmaxf(m, f[i]);
    m = fmaxf(m, __shfl_xor(m, 16));
    m = fmaxf(m, __shfl_xor(m, 32));
    float s = 0.f;
#pragma unroll
    for (int i = 0; i < 16; i++) {
      f[i] = __expf(f[i] - m);
      s += f[i];
    }
    s += __shfl_xor(s, 16);
    s += __shfl_xor(s, 32);
    float inv = 1.f / s;
    short8v A0, A1;
#pragma unroll
    for (int i = 0; i < 8; i++) {
      A0[i] = f2bf(f[i] * inv);
      A1[i] = f2bf(f[8 + i] * inv);
    }
#pragma unroll
    for (int ni = 0; ni < 4; ni++) {
      acc[mi][ni] = __builtin_amdgcn_mfma_f32_16x16x32_bf16(A0, bb[0][ni], acc[mi][ni], 0, 0, 0);
      acc[mi][ni] = __builtin_amdgcn_mfma_f32_16x16x32_bf16(A1, bb[1][ni], acc[mi][ni], 0, 0, 0);
    }
  }
#pragma unroll
  for (int mi = 0; mi < 4; mi++)
#pragma unroll
    for (int ni = 0; ni < 4; ni++)
#pragma unroll
      for (int r = 0; r < 4; r++) {
        int row = w * 64 + mi * 16 + kg * 4 + r;
        int col = ni * 16 + r16;
        att[(size_t)(b * NN3 + row) * BDIM + h * DK + col] =
            __float2bfloat16(acc[mi][ni][r]);
      }
}

// ============ fused LN3 + MLP (gelu) + residual =============================
// Per block: 128 rows. LDS: Yn[128][512] bf16 (XOR-swz, 128KB) + h[128][128]
// bf16 (XOR-swz, 32KB) = 160KB. 8 waves as 2x4 (wr: 64 rows, wc: 32 hid /
// 128 out cols). 16 hidden chunks of 128.
__global__ __launch_bounds__(512, 2) void fused_mlp_kernel(
    const bf16* __restrict__ f3o, const bf16* __restrict__ W1gt,
    const bf16* __restrict__ W2t, const float* __restrict__ b1p,
    const float* __restrict__ b2, float* __restrict__ out) {
  extern __shared__ char ldsY[];            // 131072 B
  char* ldsH = ldsY + 131072;               // 32768 B

  int t = threadIdx.x, w = t >> 6, lane = t & 63;
  int wr = w >> 2, wc = w & 3;
  int r16 = lane & 15, kg = lane >> 4;
  int rowbase = blockIdx.x * 128;

  // ---- stage f3o rows -> ldsY (linear dest, inverse-swizzled source) ----
  // granule idx = iter*512 + t; row = idx>>6 (const per wave), g = lane.
  {
    const char* src0 = (const char*)(f3o + (size_t)rowbase * BDIM);
#pragma unroll
    for (int it = 0; it < 16; it++) {
      int row = it * 8 + w;
      int sb = (lane * 16) ^ ((row & 7) << 4);
      GLOAD_LDS16(src0 + (size_t)row * 1024 + sb, ldsY + (it * 512 + t) * 16);
    }
  }
  __syncthreads();

  // ---- LN in LDS: wave w handles rows w*16 .. w*16+15 ----
  for (int r = 0; r < 16; r++) {
    int row = w * 16 + r;
    char* p = ldsY + row * 1024 + ((lane * 16) ^ ((row & 7) << 4));
    short8v v = *(short8v*)p;
    float s = 0.f, sq = 0.f;
#pragma unroll
    for (int i = 0; i < 8; i++) {
      float f = bf2f(v[i]);
      s += f;
      sq += f * f;
    }
#pragma unroll
    for (int o = 1; o <= 32; o <<= 1) {
      s += __shfl_xor(s, o);
      sq += __shfl_xor(sq, o);
    }
    float mean = s * (1.f / BDIM);
    float var = sq * (1.f / BDIM) - mean * mean;
    float rstd = rsqrtf(var + 1e-5f);
    short8v z;
#pragma unroll
    for (int i = 0; i < 8; i++) z[i] = f2bf((bf2f(v[i]) - mean) * rstd);
    *(short8v*)p = z;
  }
  __syncthreads();

  f32x4 acc2[4][8] = {};

  for (int c = 0; c < 16; c++) {
    int cbase = c * 128;
    // ---- stage 1: h[128][128] = gelu(Yn @ W1gt_c + b1p) ----
    f32x4 acc1[4][2] = {};
#pragma unroll
    for (int kk = 0; kk < 16; kk++) {
      short8v a[4], b[2];
#pragma unroll
      for (int m = 0; m < 4; m++) {
        int row = wr * 64 + m * 16 + r16;
        a[m] = *(const short8v*)(ldsY + row * 1024 +
                                 ((kk * 64 + kg * 16) ^ ((row & 7) << 4)));
      }
#pragma unroll
      for (int nt = 0; nt < 2; nt++) {
        int hc = cbase + wc * 32 + nt * 16 + r16;
        b[nt] = *(const short8v*)(W1gt + (size_t)hc * BDIM + kk * 32 + kg * 8);
      }
#pragma unroll
      for (int m = 0; m < 4; m++)
#pragma unroll
        for (int nt = 0; nt < 2; nt++)
          acc1[m][nt] =
              __builtin_amdgcn_mfma_f32_16x16x32_bf16(a[m], b[nt], acc1[m][nt], 0, 0, 0);
    }
#pragma unroll
    for (int nt = 0; nt < 2; nt++) {
      int hcl = wc * 32 + nt * 16 + r16;  // local hid col 0..127
      float b1v = b1p[cbase + hcl];
#pragma unroll
      for (int m = 0; m < 4; m++)
#pragma unroll
        for (int j = 0; j < 4; j++) {
          int row = wr * 64 + m * 16 + kg * 4 + j;
          float v = acc1[m][nt][j] + b1v;
          float gl = 0.5f * v * (1.f + erff(v * 0.70710678f));
          *(short*)(ldsH + row * 256 + ((hcl * 2) ^ ((row & 7) << 4))) = f2bf(gl);
        }
    }
    __syncthreads();
    // ---- stage 2: acc2 += h @ W2t_c ----
#pragma unroll
    for (int kk = 0; kk < 4; kk++) {
      short8v a[4], b[8];
#pragma unroll
      for (int m = 0; m < 4; m++) {
        int row = wr * 64 + m * 16 + r16;
        a[m] = *(const short8v*)(ldsH + row * 256 +
                                 ((kk * 64 + kg * 16) ^ ((row & 7) << 4)));
      }
#pragma unroll
      for (int nt = 0; nt < 8; nt++) {
        int oc = wc * 128 + nt * 16 + r16;
        b[nt] = *(const short8v*)(W2t + (size_t)oc * NMLP + cbase + kk * 32 + kg * 8);
      }
#pragma unroll
      for (int m = 0; m < 4; m++)
#pragma unroll
        for (int nt = 0; nt < 8; nt++)
          acc2[m][nt] =
              __builtin_amdgcn_mfma_f32_16x16x32_bf16(a[m], b[nt], acc2[m][nt], 0, 0, 0);
    }
    __syncthreads();
  }

  // ---- epilogue: out = f3o + acc2 + b2 (f32, write-only) ----
#pragma unroll
  for (int nt = 0; nt < 8; nt++) {
    int col = wc * 128 + nt * 16 + r16;
    float b2v = b2[col];
#pragma unroll
    for (int m = 0; m < 4; m++)
#pragma unroll
      for (int j = 0; j < 4; j++) {
        int row = rowbase + wr * 64 + m * 16 + kg * 4 + j;
        size_t o = (size_t)row * BDIM + col;
        out[o] = bf2f(*(const short*)&f3o[o]) + acc2[m][nt][j] + b2v;
      }
  }
}

extern "C" void kernel_launch(void* const* d_in, const int* in_sizes, int n_in,
                              void* d_out, int out_size, void* d_ws, size_t ws_size,
                              hipStream_t stream) {
  const float* f3 = (const float*)d_in[0];
  const float* f4 = (const float*)d_in[1];
  const float* pos3 = (const float*)d_in[2];
  const float* pos4 = (const float*)d_in[3];
  const float* ln1_g = (const float*)d_in[4];
  const float* ln1_b = (const float*)d_in[5];
  const float* ln2_g = (const float*)d_in[6];
  const float* ln2_b = (const float*)d_in[7];
  const float* ln3_g = (const float*)d_in[8];
  const float* ln3_b = (const float*)d_in[9];
  const float* Wq = (const float*)d_in[10];
  const float* bq = (const float*)d_in[11];
  const float* Wk = (const float*)d_in[12];
  const float* bk = (const float*)d_in[13];
  const float* Wv = (const float*)d_in[14];
  const float* bv = (const float*)d_in[15];
  const float* Wr = (const float*)d_in[16];
  const float* br = (const float*)d_in[17];
  const float* W1 = (const float*)d_in[18];
  const float* b1 = (const float*)d_in[19];
  const float* W2 = (const float*)d_in[20];
  const float* b2 = (const float*)d_in[21];
  float* out = (float*)d_out;

  const int M3 = NBATCH * NN3;  // 65536
  const int M4 = NBATCH * NN4;  // 16384

  char* ws = (char*)d_ws;
  size_t off = 0;
  auto alloc = [&](size_t bytes) {
    size_t r = off;
    off = (off + bytes + 255) & ~(size_t)255;
    return r;
  };
  size_t oWqt = alloc((size_t)BDIM * BDIM * 2);
  size_t oWkt = alloc((size_t)BDIM * BDIM * 2);
  size_t oWvt = alloc((size_t)BDIM * BDIM * 2);
  size_t oWrt = alloc((size_t)BDIM * BDIM * 2);
  size_t oW1t = alloc((size_t)BDIM * NMLP * 2);
  size_t oW2t = alloc((size_t)BDIM * NMLP * 2);
  size_t oB1p = alloc((size_t)NMLP * 4);
  size_t oXQ = alloc((size_t)M3 * BDIM * 2);  // ln(f3)+pos3; reused as att
  size_t oXK = alloc((size_t)M4 * BDIM * 2);
  size_t oXV = alloc((size_t)M4 * BDIM * 2);
  size_t oQF = alloc((size_t)M3 * BDIM * 2);  // raw q proj; reused as f3o
  size_t oKF = alloc((size_t)M4 * BDIM * 2);
  size_t oVF = alloc((size_t)M4 * BDIM * 2);
  size_t oCT = alloc((size_t)NBATCH * NHEADS * DK * DK * 2);
  (void)ws_size;

  bf16* Wqt = (bf16*)(ws + oWqt);
  bf16* Wkt = (bf16*)(ws + oWkt);
  bf16* Wvt = (bf16*)(ws + oWvt);
  bf16* Wrt = (bf16*)(ws + oWrt);
  bf16* W1gt = (bf16*)(ws + oW1t);
  bf16* W2t = (bf16*)(ws + oW2t);
  float* b1p = (float*)(ws + oB1p);
  bf16* XQ = (bf16*)(ws + oXQ);
  bf16* XK = (bf16*)(ws + oXK);
  bf16* XV = (bf16*)(ws + oXV);
  bf16* QF = (bf16*)(ws + oQF);
  bf16* KF = (bf16*)(ws + oKF);
  bf16* VF = (bf16*)(ws + oVF);
  bf16* CT = (bf16*)(ws + oCT);
  bf16* ATT = XQ;   // reuse (XQ dead after q projection)
  bf16* F3O = QF;   // reuse (QF dead after att)

  // ---- weight conversion / folds ----
  convert_wt_kernel<<<(BDIM * BDIM + 255) / 256, 256, 0, stream>>>(Wq, Wqt, BDIM, BDIM);
  convert_wt_kernel<<<(BDIM * BDIM + 255) / 256, 256, 0, stream>>>(Wk, Wkt, BDIM, BDIM);
  convert_wt_kernel<<<(BDIM * BDIM + 255) / 256, 256, 0, stream>>>(Wv, Wvt, BDIM, BDIM);
  convert_wt_kernel<<<(BDIM * BDIM + 255) / 256, 256, 0, stream>>>(Wr, Wrt, BDIM, BDIM);
  convert_w1g_kernel<<<(BDIM * NMLP + 255) / 256, 256, 0, stream>>>(W1, ln3_g, W1gt);
  convert_wt_kernel<<<(BDIM * NMLP + 255) / 256, 256, 0, stream>>>(W2, W2t, NMLP, BDIM);
  b1fold_kernel<<<NMLP / 256, 256, 0, stream>>>(W1, b1, ln3_b, b1p);

  // ---- layernorms ----
  ln_kernel<<<M3, 256, 0, stream>>>(f3, ln1_g, ln1_b, pos3, NN3, XQ, nullptr);
  ln_kernel<<<M4, 256, 0, stream>>>(f4, ln2_g, ln2_b, pos4, NN4, XK, XV);

  // ---- projections ----
  gemm_kernel<0><<<(BDIM / 128) * (M3 / 128), 256, 0, stream>>>(
      XQ, Wqt, bq, nullptr, QF, BDIM, BDIM, BDIM, BDIM, BDIM / 128);
  gemm_kernel<0><<<(BDIM / 128) * (M4 / 128), 256, 0, stream>>>(
      XK, Wkt, bk, nullptr, KF, BDIM, BDIM, BDIM, BDIM, BDIM / 128);
  gemm_kernel<0><<<(BDIM / 128) * (M4 / 128), 256, 0, stream>>>(
      XV, Wvt, bv, nullptr, VF, BDIM, BDIM, BDIM, BDIM, BDIM / 128);

  // ---- context (fused k-softmax) + att (fused q-softmax) ----
  ctx_kernel<<<NBATCH * NHEADS, 256, 0, stream>>>(KF, VF, CT);
  att_kernel<<<NBATCH * NHEADS, 256, 0, stream>>>(QF, CT, ATT);

  // ---- output projection: F3O(bf16) = f3 + att @ Wr + br ----
  gemm_kernel<3><<<(BDIM / 128) * (M3 / 128), 256, 0, stream>>>(
      ATT, Wrt, br, f3, F3O, BDIM, BDIM, BDIM, BDIM, BDIM / 128);

  // ---- fused LN3 + MLP + residual -> d_out (f32) ----
  hipFuncSetAttribute((const void*)fused_mlp_kernel,
                      hipFuncAttributeMaxDynamicSharedMemorySize, 163840);
  fused_mlp_kernel<<<M3 / 128, 512, 163840, stream>>>(F3O, W1gt, W2t, b1p, b2, out);
}

// Round 7
// 944.369 us; speedup vs baseline: 1.2817x; 1.2817x over previous
//
#include <hip/hip_runtime.h>
#include <hip/hip_bf16.h>

typedef __attribute__((ext_vector_type(8))) short short8v;
typedef __attribute__((ext_vector_type(4))) float f32x4;
typedef __hip_bfloat16 bf16;

#define BDIM 512
#define NHEADS 8
#define DK 64
#define NBATCH 256
#define NN3 256
#define NN4 64
#define NMLP 2048

#define GLOAD_LDS16(g, l)                                                  \
  __builtin_amdgcn_global_load_lds(                                        \
      (const __attribute__((address_space(1))) void*)(g),                  \
      (__attribute__((address_space(3))) void*)(l), 16, 0, 0)

__device__ __forceinline__ float bf2f(short s) {
  union { short u[2]; float f; } cv;
  cv.u[0] = 0; cv.u[1] = s;
  return cv.f;
}
__device__ __forceinline__ short f2bf(float x) {
  bf16 h = __float2bfloat16(x);
  return *reinterpret_cast<short*>(&h);
}

// ---------------- weight convert: Wt[n][k] = bf16(W[k][n]) ----------------
__global__ __launch_bounds__(256) void convert_wt_kernel(
    const float* __restrict__ W, bf16* __restrict__ Wt, int K, int N) {
  int idx = blockIdx.x * 256 + threadIdx.x;
  if (idx >= K * N) return;
  int n = idx / K;
  int k = idx - n * K;
  Wt[idx] = __float2bfloat16(W[(size_t)k * N + n]);
}

// ---------------- LayerNorm over 512 (f32 in), +pos, optional 2nd out -----
__global__ __launch_bounds__(256) void ln_kernel(
    const float* __restrict__ x, const float* __restrict__ g,
    const float* __restrict__ beta, const float* __restrict__ pos, int nmod,
    bf16* __restrict__ out1, bf16* __restrict__ out2) {
  int row = blockIdx.x;
  int t = threadIdx.x;
  const float* xr = x + (size_t)row * BDIM;
  float2 v = *(const float2*)(xr + t * 2);
  float s = v.x + v.y;
  float sq = v.x * v.x + v.y * v.y;
  for (int o = 32; o > 0; o >>= 1) {
    s += __shfl_down(s, o);
    sq += __shfl_down(sq, o);
  }
  __shared__ float ls[4], lq[4];
  int w = t >> 6;
  if ((t & 63) == 0) { ls[w] = s; lq[w] = sq; }
  __syncthreads();
  s = ls[0] + ls[1] + ls[2] + ls[3];
  sq = lq[0] + lq[1] + lq[2] + lq[3];
  float mean = s * (1.f / BDIM);
  float var = sq * (1.f / BDIM) - mean * mean;
  float rstd = rsqrtf(var + 1e-5f);
  int n = row % nmod;
  for (int i = 0; i < 2; i++) {
    int c = t * 2 + i;
    float xv = i ? v.y : v.x;
    float nv = (xv - mean) * rstd * g[c] + beta[c];
    if (out2) out2[(size_t)row * BDIM + c] = __float2bfloat16(nv);
    float o1 = nv + (pos ? pos[(size_t)n * BDIM + c] : 0.f);
    out1[(size_t)row * BDIM + c] = __float2bfloat16(o1);
  }
}

// ---------------- LayerNorm over 512 (bf16 in, bf16 out) ------------------
__global__ __launch_bounds__(256) void lnb_kernel(
    const bf16* __restrict__ x, const float* __restrict__ g,
    const float* __restrict__ beta, bf16* __restrict__ out) {
  int row = blockIdx.x;
  int t = threadIdx.x;
  const unsigned* xr = (const unsigned*)(x + (size_t)row * BDIM);
  unsigned u = xr[t];
  float a = bf2f((short)(u & 0xffff));
  float b = bf2f((short)(u >> 16));
  float s = a + b;
  float sq = a * a + b * b;
  for (int o = 32; o > 0; o >>= 1) {
    s += __shfl_down(s, o);
    sq += __shfl_down(sq, o);
  }
  __shared__ float ls[4], lq[4];
  int w = t >> 6;
  if ((t & 63) == 0) { ls[w] = s; lq[w] = sq; }
  __syncthreads();
  s = ls[0] + ls[1] + ls[2] + ls[3];
  sq = lq[0] + lq[1] + lq[2] + lq[3];
  float mean = s * (1.f / BDIM);
  float var = sq * (1.f / BDIM) - mean * mean;
  float rstd = rsqrtf(var + 1e-5f);
  int c = t * 2;
  unsigned r = (unsigned)(unsigned short)f2bf((a - mean) * rstd * g[c] + beta[c]) |
               ((unsigned)(unsigned short)f2bf((b - mean) * rstd * g[c + 1] + beta[c + 1]) << 16);
  ((unsigned*)(out + (size_t)row * BDIM))[t] = r;
}

// ---------------- pipelined MFMA GEMM: out[M,N] = X[M,K] @ Wt[N,K]^T ------
// 128x128 tile, 8 waves (2x4), BK=64, 4 LDS buffers, depth-2 counted-vmcnt
// prefetch with raw s_barrier (loads stay in flight across barriers).
// EPI 0: bf16 out = acc + bias
// EPI 1: bf16 out = gelu(acc + bias)
// EPI 3: bf16 out = srcf32[o] + acc + bias
// EPI 4: f32  out = srcbf16[o] + acc + bias
template <int EPI>
__global__ __launch_bounds__(512) void gemm_kernel(
    const bf16* __restrict__ X, const bf16* __restrict__ Wt,
    const float* __restrict__ bias, const void* __restrict__ src, void* outp,
    int K, int ldx, int ldw, int N, int gridX) {
  extern __shared__ bf16 lds[];  // 4 x 16384 elements (A 8192 + B 8192) = 128KB

  // XCD-aware bijective swizzle (nwg % 8 == 0 for all launches)
  int nwg = gridDim.x;
  int cpx = nwg >> 3;
  int bid = blockIdx.x;
  int nb = (bid & 7) * cpx + (bid >> 3);
  int bx = nb % gridX, by = nb / gridX;
  int row0 = by * 128, col0 = bx * 128;

  int t = threadIdx.x, w = t >> 6, lane = t & 63;
  int wr = w >> 2, wc = w & 3;           // 2 row-groups x 4 col-groups
  int r16 = lane & 15, kg = lane >> 4;
  int srow = lane >> 3;                   // 0..7
  int scol = ((lane & 7) ^ srow) * 8;     // inverse-swizzled source col (elems)

  // wave w stages A rows [w*16, w*16+16) and B rows [w*16, w*16+16)
  const bf16* gA0 = X + (size_t)(row0 + w * 16 + srow) * ldx + scol;
  const bf16* gB0 = Wt + (size_t)(col0 + w * 16 + srow) * ldw + scol;

  f32x4 acc[4][2] = {};

  auto stage = [&](int kt, int buf) {
    bf16* base = lds + buf * 16384;
    int ke = kt << 6;
#pragma unroll
    for (int j = 0; j < 2; j++) {
      GLOAD_LDS16(gA0 + ke + (size_t)j * 8 * ldx, base + (w * 16 + j * 8) * 64);
      GLOAD_LDS16(gB0 + ke + (size_t)j * 8 * ldw,
                  base + 8192 + (w * 16 + j * 8) * 64);
    }
  };

  auto compute = [&](int buf) {
    const char* base = (const char*)(lds + buf * 16384);
#pragma unroll
    for (int ksub = 0; ksub < 2; ksub++) {
      int cc = (ksub * 64 + kg * 16) ^ ((r16 & 7) << 4);
      short8v a[4], b[2];
#pragma unroll
      for (int m = 0; m < 4; m++)
        a[m] = *(const short8v*)(base + (wr * 64 + m * 16 + r16) * 128 + cc);
#pragma unroll
      for (int n = 0; n < 2; n++)
        b[n] = *(const short8v*)(base + 16384 + (wc * 32 + n * 16 + r16) * 128 + cc);
#pragma unroll
      for (int m = 0; m < 4; m++)
#pragma unroll
        for (int n = 0; n < 2; n++)
          acc[m][n] =
              __builtin_amdgcn_mfma_f32_16x16x32_bf16(a[m], b[n], acc[m][n], 0, 0, 0);
    }
  };

  int NT = K >> 6;
  stage(0, 0);
  if (NT > 1) stage(1, 1);
  if (NT > 2) stage(2, 2);
  for (int tt = 0; tt < NT; tt++) {
    int rem = NT - 1 - tt;
    // wait until THIS tile's 4 loads (per wave) are done; keep up to 8 in flight
    if (rem >= 2)
      asm volatile("s_waitcnt vmcnt(8)" ::: "memory");
    else if (rem == 1)
      asm volatile("s_waitcnt vmcnt(4)" ::: "memory");
    else
      asm volatile("s_waitcnt vmcnt(0)" ::: "memory");
    __builtin_amdgcn_s_barrier();  // all waves' tile-tt loads done; buf (tt-1)&3 free
    if (tt + 3 < NT) stage(tt + 3, (tt + 3) & 3);
    compute(tt & 3);
  }

#pragma unroll
  for (int n = 0; n < 2; n++) {
    int col = col0 + wc * 32 + n * 16 + r16;
    float bv = bias ? bias[col] : 0.f;
#pragma unroll
    for (int m = 0; m < 4; m++)
#pragma unroll
      for (int r = 0; r < 4; r++) {
        int row = row0 + wr * 64 + m * 16 + kg * 4 + r;
        size_t o = (size_t)row * N + col;
        float val = acc[m][n][r] + bv;
        if (EPI == 0) {
          ((bf16*)outp)[o] = __float2bfloat16(val);
        } else if (EPI == 1) {
          float gl = 0.5f * val * (1.f + erff(val * 0.70710678f));
          ((bf16*)outp)[o] = __float2bfloat16(gl);
        } else if (EPI == 3) {
          ((bf16*)outp)[o] = __float2bfloat16(((const float*)src)[o] + val);
        } else {
          ((float*)outp)[o] = bf2f(((const short*)src)[o]) + val;
        }
      }
  }
}

// ---- ctx: fused k-softmax (over positions) + ctxT[bh][vc][kc] einsum -----
__global__ __launch_bounds__(256) void ctx_kernel(
    const bf16* __restrict__ kproj, const bf16* __restrict__ vbuf,
    bf16* __restrict__ ctxT) {
  int bh = blockIdx.x;
  int b = bh >> 3, h = bh & 7;
  __shared__ bf16 lk[NN4][DK], lv[NN4][DK];
  int t = threadIdx.x;
#pragma unroll
  for (int i = 0; i < 16; i++) {
    int idx = i * 256 + t;
    int n = idx >> 6, c = idx & 63;
    size_t gaddr = (size_t)b * NN4 * BDIM + (size_t)n * BDIM + h * DK + c;
    lk[n][c] = kproj[gaddr];
    lv[n][c] = vbuf[gaddr];
  }
  __syncthreads();
  if (t < 64) {
    int c = t;
    float e[NN4];
    float m = -1e30f;
#pragma unroll
    for (int n = 0; n < NN4; n++) {
      e[n] = bf2f(*(short*)&lk[n][c]);
      m = fmaxf(m, e[n]);
    }
    float s = 0.f;
#pragma unroll
    for (int n = 0; n < NN4; n++) {
      e[n] = __expf(e[n] - m);
      s += e[n];
    }
    float inv = 1.f / s;
#pragma unroll
    for (int n = 0; n < NN4; n++) lk[n][c] = __float2bfloat16(e[n] * inv);
  }
  __syncthreads();
  int vc = t >> 2;
  int kc0 = (t & 3) * 16;
  float acc[16] = {};
  for (int n = 0; n < NN4; n++) {
    float vv = __bfloat162float(lv[n][vc]);
#pragma unroll
    for (int i = 0; i < 16; i++)
      acc[i] += vv * __bfloat162float(lk[n][kc0 + i]);
  }
  size_t o = (size_t)bh * 4096 + (size_t)vc * 64 + kc0;
#pragma unroll
  for (int i = 0; i < 16; i++) ctxT[o + i] = __float2bfloat16(acc[i]);
}

// ---- att: fused q-softmax (in-register, over 64 head channels) + GEMM ----
__global__ __launch_bounds__(256) void att_kernel(
    const bf16* __restrict__ qproj, const bf16* __restrict__ ctxT,
    bf16* __restrict__ att) {
  int bh = blockIdx.x;
  int b = bh >> 3, h = bh & 7;
  int t = threadIdx.x, w = t >> 6, lane = t & 63;
  int r16 = lane & 15, kg = lane >> 4;
  f32x4 acc[4][4] = {};
  const bf16* qb = qproj + (size_t)b * NN3 * BDIM + h * DK;
  const bf16* cb = ctxT + (size_t)bh * 4096;
  short8v bb[2][4];
#pragma unroll
  for (int kt = 0; kt < 2; kt++)
#pragma unroll
    for (int ni = 0; ni < 4; ni++)
      bb[kt][ni] = *(const short8v*)(cb + (ni * 16 + r16) * 64 + kt * 32 + kg * 8);
#pragma unroll
  for (int mi = 0; mi < 4; mi++) {
    int rrow = w * 64 + mi * 16 + r16;
    short8v a0 = *(const short8v*)(qb + (size_t)rrow * BDIM + kg * 8);
    short8v a1 = *(const short8v*)(qb + (size_t)rrow * BDIM + 32 + kg * 8);
    float f[16];
#pragma unroll
    for (int i = 0; i < 8; i++) {
      f[i] = bf2f(a0[i]);
      f[8 + i] = bf2f(a1[i]);
    }
    float m = f[0];
#pragma unroll
    for (int i = 1; i < 16; i++) m = fmaxf(m, f[i]);
    m = fmaxf(m, __shfl_xor(m, 16));
    m = fmaxf(m, __shfl_xor(m, 32));
    float s = 0.f;
#pragma unroll
    for (int i = 0; i < 16; i++) {
      f[i] = __expf(f[i] - m);
      s += f[i];
    }
    s += __shfl_xor(s, 16);
    s += __shfl_xor(s, 32);
    float inv = 1.f / s;
    short8v A0, A1;
#pragma unroll
    for (int i = 0; i < 8; i++) {
      A0[i] = f2bf(f[i] * inv);
      A1[i] = f2bf(f[8 + i] * inv);
    }
#pragma unroll
    for (int ni = 0; ni < 4; ni++) {
      acc[mi][ni] = __builtin_amdgcn_mfma_f32_16x16x32_bf16(A0, bb[0][ni], acc[mi][ni], 0, 0, 0);
      acc[mi][ni] = __builtin_amdgcn_mfma_f32_16x16x32_bf16(A1, bb[1][ni], acc[mi][ni], 0, 0, 0);
    }
  }
#pragma unroll
  for (int mi = 0; mi < 4; mi++)
#pragma unroll
    for (int ni = 0; ni < 4; ni++)
#pragma unroll
      for (int r = 0; r < 4; r++) {
        int row = w * 64 + mi * 16 + kg * 4 + r;
        int col = ni * 16 + r16;
        att[(size_t)(b * NN3 + row) * BDIM + h * DK + col] =
            __float2bfloat16(acc[mi][ni][r]);
      }
}

extern "C" void kernel_launch(void* const* d_in, const int* in_sizes, int n_in,
                              void* d_out, int out_size, void* d_ws, size_t ws_size,
                              hipStream_t stream) {
  const float* f3 = (const float*)d_in[0];
  const float* f4 = (const float*)d_in[1];
  const float* pos3 = (const float*)d_in[2];
  const float* pos4 = (const float*)d_in[3];
  const float* ln1_g = (const float*)d_in[4];
  const float* ln1_b = (const float*)d_in[5];
  const float* ln2_g = (const float*)d_in[6];
  const float* ln2_b = (const float*)d_in[7];
  const float* ln3_g = (const float*)d_in[8];
  const float* ln3_b = (const float*)d_in[9];
  const float* Wq = (const float*)d_in[10];
  const float* bq = (const float*)d_in[11];
  const float* Wk = (const float*)d_in[12];
  const float* bk = (const float*)d_in[13];
  const float* Wv = (const float*)d_in[14];
  const float* bv = (const float*)d_in[15];
  const float* Wr = (const float*)d_in[16];
  const float* br = (const float*)d_in[17];
  const float* W1 = (const float*)d_in[18];
  const float* b1 = (const float*)d_in[19];
  const float* W2 = (const float*)d_in[20];
  const float* b2 = (const float*)d_in[21];
  float* out = (float*)d_out;

  const int M3 = NBATCH * NN3;  // 65536
  const int M4 = NBATCH * NN4;  // 16384
  const int MC = M3 / 2;        // 32768 MLP row-chunk

  char* ws = (char*)d_ws;
  size_t off = 0;
  auto alloc = [&](size_t bytes) {
    size_t r = off;
    off = (off + bytes + 255) & ~(size_t)255;
    return r;
  };
  size_t oWqt = alloc((size_t)BDIM * BDIM * 2);
  size_t oWkt = alloc((size_t)BDIM * BDIM * 2);
  size_t oWvt = alloc((size_t)BDIM * BDIM * 2);
  size_t oWrt = alloc((size_t)BDIM * BDIM * 2);
  size_t oW1t = alloc((size_t)BDIM * NMLP * 2);
  size_t oW2t = alloc((size_t)BDIM * NMLP * 2);
  size_t oXQ = alloc((size_t)M3 * BDIM * 2);  // ln(f3)+pos3 -> att -> Yn
  size_t oXK = alloc((size_t)M4 * BDIM * 2);
  size_t oXV = alloc((size_t)M4 * BDIM * 2);
  size_t oQF = alloc((size_t)M3 * BDIM * 2);  // q proj -> F3O
  size_t oKF = alloc((size_t)M4 * BDIM * 2);
  size_t oVF = alloc((size_t)M4 * BDIM * 2);
  size_t oCT = alloc((size_t)NBATCH * NHEADS * DK * DK * 2);
  size_t oH1 = alloc((size_t)MC * NMLP * 2);  // 128MB hidden row-chunk
  (void)ws_size;

  bf16* Wqt = (bf16*)(ws + oWqt);
  bf16* Wkt = (bf16*)(ws + oWkt);
  bf16* Wvt = (bf16*)(ws + oWvt);
  bf16* Wrt = (bf16*)(ws + oWrt);
  bf16* W1t = (bf16*)(ws + oW1t);
  bf16* W2t = (bf16*)(ws + oW2t);
  bf16* XQ = (bf16*)(ws + oXQ);
  bf16* XK = (bf16*)(ws + oXK);
  bf16* XV = (bf16*)(ws + oXV);
  bf16* QF = (bf16*)(ws + oQF);
  bf16* KF = (bf16*)(ws + oKF);
  bf16* VF = (bf16*)(ws + oVF);
  bf16* CT = (bf16*)(ws + oCT);
  bf16* H1 = (bf16*)(ws + oH1);
  bf16* ATT = XQ;   // reuse (XQ dead after q projection)
  bf16* F3O = QF;   // reuse (QF dead after att)
  bf16* YN = XQ;    // reuse (ATT dead after outproj)

  // dynamic-LDS cap for the 128KB GEMM
  hipFuncSetAttribute((const void*)gemm_kernel<0>,
                      hipFuncAttributeMaxDynamicSharedMemorySize, 131072);
  hipFuncSetAttribute((const void*)gemm_kernel<1>,
                      hipFuncAttributeMaxDynamicSharedMemorySize, 131072);
  hipFuncSetAttribute((const void*)gemm_kernel<3>,
                      hipFuncAttributeMaxDynamicSharedMemorySize, 131072);
  hipFuncSetAttribute((const void*)gemm_kernel<4>,
                      hipFuncAttributeMaxDynamicSharedMemorySize, 131072);

  // ---- weight conversion ----
  convert_wt_kernel<<<(BDIM * BDIM + 255) / 256, 256, 0, stream>>>(Wq, Wqt, BDIM, BDIM);
  convert_wt_kernel<<<(BDIM * BDIM + 255) / 256, 256, 0, stream>>>(Wk, Wkt, BDIM, BDIM);
  convert_wt_kernel<<<(BDIM * BDIM + 255) / 256, 256, 0, stream>>>(Wv, Wvt, BDIM, BDIM);
  convert_wt_kernel<<<(BDIM * BDIM + 255) / 256, 256, 0, stream>>>(Wr, Wrt, BDIM, BDIM);
  convert_wt_kernel<<<(BDIM * NMLP + 255) / 256, 256, 0, stream>>>(W1, W1t, BDIM, NMLP);
  convert_wt_kernel<<<(BDIM * NMLP + 255) / 256, 256, 0, stream>>>(W2, W2t, NMLP, BDIM);

  // ---- layernorms ----
  ln_kernel<<<M3, 256, 0, stream>>>(f3, ln1_g, ln1_b, pos3, NN3, XQ, nullptr);
  ln_kernel<<<M4, 256, 0, stream>>>(f4, ln2_g, ln2_b, pos4, NN4, XK, XV);

  // ---- projections ----
  gemm_kernel<0><<<(BDIM / 128) * (M3 / 128), 512, 131072, stream>>>(
      XQ, Wqt, bq, nullptr, QF, BDIM, BDIM, BDIM, BDIM, BDIM / 128);
  gemm_kernel<0><<<(BDIM / 128) * (M4 / 128), 512, 131072, stream>>>(
      XK, Wkt, bk, nullptr, KF, BDIM, BDIM, BDIM, BDIM, BDIM / 128);
  gemm_kernel<0><<<(BDIM / 128) * (M4 / 128), 512, 131072, stream>>>(
      XV, Wvt, bv, nullptr, VF, BDIM, BDIM, BDIM, BDIM, BDIM / 128);

  // ---- context (fused k-softmax) + att (fused q-softmax) ----
  ctx_kernel<<<NBATCH * NHEADS, 256, 0, stream>>>(KF, VF, CT);
  att_kernel<<<NBATCH * NHEADS, 256, 0, stream>>>(QF, CT, ATT);

  // ---- output projection: F3O(bf16) = f3(f32) + att @ Wr + br ----
  gemm_kernel<3><<<(BDIM / 128) * (M3 / 128), 512, 131072, stream>>>(
      ATT, Wrt, br, f3, F3O, BDIM, BDIM, BDIM, BDIM, BDIM / 128);

  // ---- LN3: YN(bf16) = ln(F3O) ----  (YN aliases ATT, dead now)
  lnb_kernel<<<M3, 256, 0, stream>>>(F3O, ln3_g, ln3_b, YN);

  // ---- MLP, 2 row-chunks of 32768 ----
  for (int c = 0; c < 2; c++) {
    const bf16* Yc = YN + (size_t)c * MC * BDIM;
    const bf16* Fc = F3O + (size_t)c * MC * BDIM;
    float* outc = out + (size_t)c * MC * BDIM;
    gemm_kernel<1><<<(NMLP / 128) * (MC / 128), 512, 131072, stream>>>(
        Yc, W1t, b1, nullptr, H1, BDIM, BDIM, BDIM, NMLP, NMLP / 128);
    gemm_kernel<4><<<(BDIM / 128) * (MC / 128), 512, 131072, stream>>>(
        H1, W2t, b2, Fc, outc, NMLP, NMLP, NMLP, BDIM, BDIM / 128);
  }
}

// Round 8
// 876.208 us; speedup vs baseline: 1.3814x; 1.0778x over previous
//
#include <hip/hip_runtime.h>
#include <hip/hip_bf16.h>

typedef __attribute__((ext_vector_type(8))) short short8v;
typedef __attribute__((ext_vector_type(4))) float f32x4;
typedef __hip_bfloat16 bf16;

#define BDIM 512
#define NHEADS 8
#define DK 64
#define NBATCH 256
#define NN3 256
#define NN4 64
#define NMLP 2048

#define GLOAD_LDS16(g, l)                                                  \
  __builtin_amdgcn_global_load_lds(                                        \
      (const __attribute__((address_space(1))) void*)(g),                  \
      (__attribute__((address_space(3))) void*)(l), 16, 0, 0)

__device__ __forceinline__ float bf2f(short s) {
  union { short u[2]; float f; } cv;
  cv.u[0] = 0; cv.u[1] = s;
  return cv.f;
}
__device__ __forceinline__ short f2bf(float x) {
  bf16 h = __float2bfloat16(x);
  return *reinterpret_cast<short*>(&h);
}

// ---------------- weight convert: Wt[n][k] = bf16(W[k][n]) ----------------
__global__ __launch_bounds__(256) void convert_wt_kernel(
    const float* __restrict__ W, bf16* __restrict__ Wt, int K, int N) {
  int idx = blockIdx.x * 256 + threadIdx.x;
  if (idx >= K * N) return;
  int n = idx / K;
  int k = idx - n * K;
  Wt[idx] = __float2bfloat16(W[(size_t)k * N + n]);
}

// ------- LayerNorm over 512 (f32 in), +pos, optional extra outputs --------
__global__ __launch_bounds__(256) void ln_kernel(
    const float* __restrict__ x, const float* __restrict__ g,
    const float* __restrict__ beta, const float* __restrict__ pos, int nmod,
    bf16* __restrict__ out1, bf16* __restrict__ out2, bf16* __restrict__ raw) {
  int row = blockIdx.x;
  int t = threadIdx.x;
  const float* xr = x + (size_t)row * BDIM;
  float2 v = *(const float2*)(xr + t * 2);
  float s = v.x + v.y;
  float sq = v.x * v.x + v.y * v.y;
  for (int o = 32; o > 0; o >>= 1) {
    s += __shfl_down(s, o);
    sq += __shfl_down(sq, o);
  }
  __shared__ float ls[4], lq[4];
  int w = t >> 6;
  if ((t & 63) == 0) { ls[w] = s; lq[w] = sq; }
  __syncthreads();
  s = ls[0] + ls[1] + ls[2] + ls[3];
  sq = lq[0] + lq[1] + lq[2] + lq[3];
  float mean = s * (1.f / BDIM);
  float var = sq * (1.f / BDIM) - mean * mean;
  float rstd = rsqrtf(var + 1e-5f);
  int n = row % nmod;
  for (int i = 0; i < 2; i++) {
    int c = t * 2 + i;
    float xv = i ? v.y : v.x;
    if (raw) raw[(size_t)row * BDIM + c] = __float2bfloat16(xv);
    float nv = (xv - mean) * rstd * g[c] + beta[c];
    if (out2) out2[(size_t)row * BDIM + c] = __float2bfloat16(nv);
    float o1 = nv + (pos ? pos[(size_t)n * BDIM + c] : 0.f);
    out1[(size_t)row * BDIM + c] = __float2bfloat16(o1);
  }
}

// ---------------- LayerNorm over 512 (bf16 in, bf16 out) ------------------
__global__ __launch_bounds__(256) void lnb_kernel(
    const bf16* __restrict__ x, const float* __restrict__ g,
    const float* __restrict__ beta, bf16* __restrict__ out) {
  int row = blockIdx.x;
  int t = threadIdx.x;
  const unsigned* xr = (const unsigned*)(x + (size_t)row * BDIM);
  unsigned u = xr[t];
  float a = bf2f((short)(u & 0xffff));
  float b = bf2f((short)(u >> 16));
  float s = a + b;
  float sq = a * a + b * b;
  for (int o = 32; o > 0; o >>= 1) {
    s += __shfl_down(s, o);
    sq += __shfl_down(sq, o);
  }
  __shared__ float ls[4], lq[4];
  int w = t >> 6;
  if ((t & 63) == 0) { ls[w] = s; lq[w] = sq; }
  __syncthreads();
  s = ls[0] + ls[1] + ls[2] + ls[3];
  sq = lq[0] + lq[1] + lq[2] + lq[3];
  float mean = s * (1.f / BDIM);
  float var = sq * (1.f / BDIM) - mean * mean;
  float rstd = rsqrtf(var + 1e-5f);
  int c = t * 2;
  unsigned r = (unsigned)(unsigned short)f2bf((a - mean) * rstd * g[c] + beta[c]) |
               ((unsigned)(unsigned short)f2bf((b - mean) * rstd * g[c + 1] + beta[c + 1]) << 16);
  ((unsigned*)(out + (size_t)row * BDIM))[t] = r;
}

// ---------------- pipelined MFMA GEMM: out[M,N] = X[M,K] @ Wt[N,K]^T ------
// 128x128 tile, 8 waves (2x4), BK=64, 2 LDS buffers (64KB -> 2 blocks/CU),
// counted-vmcnt depth-2 prefetch, 2 raw barriers per K-step.
// EPI 0: bf16 out = acc + bias
// EPI 1: bf16 out = gelu(acc + bias)
// EPI 3: bf16 out = srcbf16[o] + acc + bias
// EPI 4: f32  out = srcbf16[o] + acc + bias
template <int EPI>
__global__ __launch_bounds__(512) void gemm_kernel(
    const bf16* __restrict__ X, const bf16* __restrict__ Wt,
    const float* __restrict__ bias, const void* __restrict__ src, void* outp,
    int K, int ldx, int ldw, int N, int gridX) {
  extern __shared__ bf16 lds[];  // 2 x 16384 elements (A 8192 + B 8192) = 64KB

  // XCD-aware bijective swizzle (nwg % 8 == 0 for all launches)
  int nwg = gridDim.x;
  int cpx = nwg >> 3;
  int bid = blockIdx.x;
  int nb = (bid & 7) * cpx + (bid >> 3);
  int bx = nb % gridX, by = nb / gridX;
  int row0 = by * 128, col0 = bx * 128;

  int t = threadIdx.x, w = t >> 6, lane = t & 63;
  int wr = w >> 2, wc = w & 3;           // 2 row-groups x 4 col-groups
  int r16 = lane & 15, kg = lane >> 4;
  int srow = lane >> 3;                   // 0..7
  int scol = ((lane & 7) ^ srow) * 8;     // inverse-swizzled source col (elems)

  // wave w stages A rows [w*16, w*16+16) and B rows [w*16, w*16+16)
  const bf16* gA0 = X + (size_t)(row0 + w * 16 + srow) * ldx + scol;
  const bf16* gB0 = Wt + (size_t)(col0 + w * 16 + srow) * ldw + scol;

  f32x4 acc[4][2] = {};

  auto stage = [&](int kt, int buf) {
    bf16* base = lds + buf * 16384;
    int ke = kt << 6;
#pragma unroll
    for (int j = 0; j < 2; j++) {
      GLOAD_LDS16(gA0 + ke + (size_t)j * 8 * ldx, base + (w * 16 + j * 8) * 64);
      GLOAD_LDS16(gB0 + ke + (size_t)j * 8 * ldw,
                  base + 8192 + (w * 16 + j * 8) * 64);
    }
  };

  auto compute = [&](int buf) {
    const char* base = (const char*)(lds + buf * 16384);
#pragma unroll
    for (int ksub = 0; ksub < 2; ksub++) {
      int cc = (ksub * 64 + kg * 16) ^ ((r16 & 7) << 4);
      short8v a[4], b[2];
#pragma unroll
      for (int m = 0; m < 4; m++)
        a[m] = *(const short8v*)(base + (wr * 64 + m * 16 + r16) * 128 + cc);
#pragma unroll
      for (int n = 0; n < 2; n++)
        b[n] = *(const short8v*)(base + 16384 + (wc * 32 + n * 16 + r16) * 128 + cc);
#pragma unroll
      for (int m = 0; m < 4; m++)
#pragma unroll
        for (int n = 0; n < 2; n++)
          acc[m][n] =
              __builtin_amdgcn_mfma_f32_16x16x32_bf16(a[m], b[n], acc[m][n], 0, 0, 0);
    }
  };

  int NT = K >> 6;
  stage(0, 0);
  stage(1, 1);
  for (int tt = 0; tt < NT; tt++) {
    // tile tt landed (4 loads/wave/tile; tile tt+1's 4 may stay in flight)
    if (tt < NT - 1)
      asm volatile("s_waitcnt vmcnt(4)" ::: "memory");
    else
      asm volatile("s_waitcnt vmcnt(0)" ::: "memory");
    __builtin_amdgcn_s_barrier();        // all waves' tile-tt loads visible
    asm volatile("" ::: "memory");
    compute(tt & 1);
    asm volatile("" ::: "memory");
    __builtin_amdgcn_s_barrier();        // all waves done reading buf tt&1
    asm volatile("" ::: "memory");
    if (tt + 2 < NT) stage(tt + 2, tt & 1);  // overlaps compute(tt+1)
  }

#pragma unroll
  for (int n = 0; n < 2; n++) {
    int col = col0 + wc * 32 + n * 16 + r16;
    float bv = bias ? bias[col] : 0.f;
#pragma unroll
    for (int m = 0; m < 4; m++)
#pragma unroll
      for (int r = 0; r < 4; r++) {
        int row = row0 + wr * 64 + m * 16 + kg * 4 + r;
        size_t o = (size_t)row * N + col;
        float val = acc[m][n][r] + bv;
        if (EPI == 0) {
          ((bf16*)outp)[o] = __float2bfloat16(val);
        } else if (EPI == 1) {
          float gl = 0.5f * val * (1.f + erff(val * 0.70710678f));
          ((bf16*)outp)[o] = __float2bfloat16(gl);
        } else if (EPI == 3) {
          ((bf16*)outp)[o] = __float2bfloat16(bf2f(((const short*)src)[o]) + val);
        } else {
          ((float*)outp)[o] = bf2f(((const short*)src)[o]) + val;
        }
      }
  }
}

// ---- ctx: fused k-softmax (over positions) + ctxT[bh][vc][kc] einsum -----
__global__ __launch_bounds__(256) void ctx_kernel(
    const bf16* __restrict__ kproj, const bf16* __restrict__ vbuf,
    bf16* __restrict__ ctxT) {
  int bh = blockIdx.x;
  int b = bh >> 3, h = bh & 7;
  __shared__ bf16 lk[NN4][DK], lv[NN4][DK];
  int t = threadIdx.x;
#pragma unroll
  for (int i = 0; i < 16; i++) {
    int idx = i * 256 + t;
    int n = idx >> 6, c = idx & 63;
    size_t gaddr = (size_t)b * NN4 * BDIM + (size_t)n * BDIM + h * DK + c;
    lk[n][c] = kproj[gaddr];
    lv[n][c] = vbuf[gaddr];
  }
  __syncthreads();
  if (t < 64) {
    int c = t;
    float e[NN4];
    float m = -1e30f;
#pragma unroll
    for (int n = 0; n < NN4; n++) {
      e[n] = bf2f(*(short*)&lk[n][c]);
      m = fmaxf(m, e[n]);
    }
    float s = 0.f;
#pragma unroll
    for (int n = 0; n < NN4; n++) {
      e[n] = __expf(e[n] - m);
      s += e[n];
    }
    float inv = 1.f / s;
#pragma unroll
    for (int n = 0; n < NN4; n++) lk[n][c] = __float2bfloat16(e[n] * inv);
  }
  __syncthreads();
  int vc = t >> 2;
  int kc0 = (t & 3) * 16;
  float acc[16] = {};
  for (int n = 0; n < NN4; n++) {
    float vv = __bfloat162float(lv[n][vc]);
#pragma unroll
    for (int i = 0; i < 16; i++)
      acc[i] += vv * __bfloat162float(lk[n][kc0 + i]);
  }
  size_t o = (size_t)bh * 4096 + (size_t)vc * 64 + kc0;
#pragma unroll
  for (int i = 0; i < 16; i++) ctxT[o + i] = __float2bfloat16(acc[i]);
}

// ---- att: fused q-softmax (in-register, over 64 head channels) + GEMM ----
__global__ __launch_bounds__(256) void att_kernel(
    const bf16* __restrict__ qproj, const bf16* __restrict__ ctxT,
    bf16* __restrict__ att) {
  int bh = blockIdx.x;
  int b = bh >> 3, h = bh & 7;
  int t = threadIdx.x, w = t >> 6, lane = t & 63;
  int r16 = lane & 15, kg = lane >> 4;
  f32x4 acc[4][4] = {};
  const bf16* qb = qproj + (size_t)b * NN3 * BDIM + h * DK;
  const bf16* cb = ctxT + (size_t)bh * 4096;
  short8v bb[2][4];
#pragma unroll
  for (int kt = 0; kt < 2; kt++)
#pragma unroll
    for (int ni = 0; ni < 4; ni++)
      bb[kt][ni] = *(const short8v*)(cb + (ni * 16 + r16) * 64 + kt * 32 + kg * 8);
#pragma unroll
  for (int mi = 0; mi < 4; mi++) {
    int rrow = w * 64 + mi * 16 + r16;
    short8v a0 = *(const short8v*)(qb + (size_t)rrow * BDIM + kg * 8);
    short8v a1 = *(const short8v*)(qb + (size_t)rrow * BDIM + 32 + kg * 8);
    float f[16];
#pragma unroll
    for (int i = 0; i < 8; i++) {
      f[i] = bf2f(a0[i]);
      f[8 + i] = bf2f(a1[i]);
    }
    float m = f[0];
#pragma unroll
    for (int i = 1; i < 16; i++) m = fmaxf(m, f[i]);
    m = fmaxf(m, __shfl_xor(m, 16));
    m = fmaxf(m, __shfl_xor(m, 32));
    float s = 0.f;
#pragma unroll
    for (int i = 0; i < 16; i++) {
      f[i] = __expf(f[i] - m);
      s += f[i];
    }
    s += __shfl_xor(s, 16);
    s += __shfl_xor(s, 32);
    float inv = 1.f / s;
    short8v A0, A1;
#pragma unroll
    for (int i = 0; i < 8; i++) {
      A0[i] = f2bf(f[i] * inv);
      A1[i] = f2bf(f[8 + i] * inv);
    }
#pragma unroll
    for (int ni = 0; ni < 4; ni++) {
      acc[mi][ni] = __builtin_amdgcn_mfma_f32_16x16x32_bf16(A0, bb[0][ni], acc[mi][ni], 0, 0, 0);
      acc[mi][ni] = __builtin_amdgcn_mfma_f32_16x16x32_bf16(A1, bb[1][ni], acc[mi][ni], 0, 0, 0);
    }
  }
#pragma unroll
  for (int mi = 0; mi < 4; mi++)
#pragma unroll
    for (int ni = 0; ni < 4; ni++)
#pragma unroll
      for (int r = 0; r < 4; r++) {
        int row = w * 64 + mi * 16 + kg * 4 + r;
        int col = ni * 16 + r16;
        att[(size_t)(b * NN3 + row) * BDIM + h * DK + col] =
            __float2bfloat16(acc[mi][ni][r]);
      }
}

extern "C" void kernel_launch(void* const* d_in, const int* in_sizes, int n_in,
                              void* d_out, int out_size, void* d_ws, size_t ws_size,
                              hipStream_t stream) {
  const float* f3 = (const float*)d_in[0];
  const float* f4 = (const float*)d_in[1];
  const float* pos3 = (const float*)d_in[2];
  const float* pos4 = (const float*)d_in[3];
  const float* ln1_g = (const float*)d_in[4];
  const float* ln1_b = (const float*)d_in[5];
  const float* ln2_g = (const float*)d_in[6];
  const float* ln2_b = (const float*)d_in[7];
  const float* ln3_g = (const float*)d_in[8];
  const float* ln3_b = (const float*)d_in[9];
  const float* Wq = (const float*)d_in[10];
  const float* bq = (const float*)d_in[11];
  const float* Wk = (const float*)d_in[12];
  const float* bk = (const float*)d_in[13];
  const float* Wv = (const float*)d_in[14];
  const float* bv = (const float*)d_in[15];
  const float* Wr = (const float*)d_in[16];
  const float* br = (const float*)d_in[17];
  const float* W1 = (const float*)d_in[18];
  const float* b1 = (const float*)d_in[19];
  const float* W2 = (const float*)d_in[20];
  const float* b2 = (const float*)d_in[21];
  float* out = (float*)d_out;

  const int M3 = NBATCH * NN3;  // 65536
  const int M4 = NBATCH * NN4;  // 16384
  const int MC = M3 / 2;        // 32768 MLP row-chunk

  char* ws = (char*)d_ws;
  size_t off = 0;
  auto alloc = [&](size_t bytes) {
    size_t r = off;
    off = (off + bytes + 255) & ~(size_t)255;
    return r;
  };
  size_t oWqt = alloc((size_t)BDIM * BDIM * 2);
  size_t oWkt = alloc((size_t)BDIM * BDIM * 2);
  size_t oWvt = alloc((size_t)BDIM * BDIM * 2);
  size_t oWrt = alloc((size_t)BDIM * BDIM * 2);
  size_t oW1t = alloc((size_t)BDIM * NMLP * 2);
  size_t oW2t = alloc((size_t)BDIM * NMLP * 2);
  size_t oXQ = alloc((size_t)M3 * BDIM * 2);  // ln(f3)+pos3 -> att -> Yn
  size_t oXK = alloc((size_t)M4 * BDIM * 2);
  size_t oXV = alloc((size_t)M4 * BDIM * 2);
  size_t oQF = alloc((size_t)M3 * BDIM * 2);  // q proj -> F3O
  size_t oKF = alloc((size_t)M4 * BDIM * 2);
  size_t oVF = alloc((size_t)M4 * BDIM * 2);
  size_t oF3B = alloc((size_t)M3 * BDIM * 2);  // bf16 copy of f3
  size_t oCT = alloc((size_t)NBATCH * NHEADS * DK * DK * 2);
  size_t oH1 = alloc((size_t)MC * NMLP * 2);  // 128MB hidden row-chunk
  (void)ws_size;

  bf16* Wqt = (bf16*)(ws + oWqt);
  bf16* Wkt = (bf16*)(ws + oWkt);
  bf16* Wvt = (bf16*)(ws + oWvt);
  bf16* Wrt = (bf16*)(ws + oWrt);
  bf16* W1t = (bf16*)(ws + oW1t);
  bf16* W2t = (bf16*)(ws + oW2t);
  bf16* XQ = (bf16*)(ws + oXQ);
  bf16* XK = (bf16*)(ws + oXK);
  bf16* XV = (bf16*)(ws + oXV);
  bf16* QF = (bf16*)(ws + oQF);
  bf16* KF = (bf16*)(ws + oKF);
  bf16* VF = (bf16*)(ws + oVF);
  bf16* F3B = (bf16*)(ws + oF3B);
  bf16* CT = (bf16*)(ws + oCT);
  bf16* H1 = (bf16*)(ws + oH1);
  bf16* ATT = XQ;   // reuse (XQ dead after q projection)
  bf16* F3O = QF;   // reuse (QF dead after att)
  bf16* YN = XQ;    // reuse (ATT dead after outproj)

  // dynamic-LDS cap for the 64KB GEMM
  hipFuncSetAttribute((const void*)gemm_kernel<0>,
                      hipFuncAttributeMaxDynamicSharedMemorySize, 65536);
  hipFuncSetAttribute((const void*)gemm_kernel<1>,
                      hipFuncAttributeMaxDynamicSharedMemorySize, 65536);
  hipFuncSetAttribute((const void*)gemm_kernel<3>,
                      hipFuncAttributeMaxDynamicSharedMemorySize, 65536);
  hipFuncSetAttribute((const void*)gemm_kernel<4>,
                      hipFuncAttributeMaxDynamicSharedMemorySize, 65536);

  // ---- weight conversion ----
  convert_wt_kernel<<<(BDIM * BDIM + 255) / 256, 256, 0, stream>>>(Wq, Wqt, BDIM, BDIM);
  convert_wt_kernel<<<(BDIM * BDIM + 255) / 256, 256, 0, stream>>>(Wk, Wkt, BDIM, BDIM);
  convert_wt_kernel<<<(BDIM * BDIM + 255) / 256, 256, 0, stream>>>(Wv, Wvt, BDIM, BDIM);
  convert_wt_kernel<<<(BDIM * BDIM + 255) / 256, 256, 0, stream>>>(Wr, Wrt, BDIM, BDIM);
  convert_wt_kernel<<<(BDIM * NMLP + 255) / 256, 256, 0, stream>>>(W1, W1t, BDIM, NMLP);
  convert_wt_kernel<<<(BDIM * NMLP + 255) / 256, 256, 0, stream>>>(W2, W2t, NMLP, BDIM);

  // ---- layernorms (f3 pass also emits bf16 raw copy for residual) ----
  ln_kernel<<<M3, 256, 0, stream>>>(f3, ln1_g, ln1_b, pos3, NN3, XQ, nullptr, F3B);
  ln_kernel<<<M4, 256, 0, stream>>>(f4, ln2_g, ln2_b, pos4, NN4, XK, XV, nullptr);

  // ---- projections ----
  gemm_kernel<0><<<(BDIM / 128) * (M3 / 128), 512, 65536, stream>>>(
      XQ, Wqt, bq, nullptr, QF, BDIM, BDIM, BDIM, BDIM, BDIM / 128);
  gemm_kernel<0><<<(BDIM / 128) * (M4 / 128), 512, 65536, stream>>>(
      XK, Wkt, bk, nullptr, KF, BDIM, BDIM, BDIM, BDIM, BDIM / 128);
  gemm_kernel<0><<<(BDIM / 128) * (M4 / 128), 512, 65536, stream>>>(
      XV, Wvt, bv, nullptr, VF, BDIM, BDIM, BDIM, BDIM, BDIM / 128);

  // ---- context (fused k-softmax) + att (fused q-softmax) ----
  ctx_kernel<<<NBATCH * NHEADS, 256, 0, stream>>>(KF, VF, CT);
  att_kernel<<<NBATCH * NHEADS, 256, 0, stream>>>(QF, CT, ATT);

  // ---- output projection: F3O(bf16) = f3(bf16 copy) + att @ Wr + br ----
  gemm_kernel<3><<<(BDIM / 128) * (M3 / 128), 512, 65536, stream>>>(
      ATT, Wrt, br, F3B, F3O, BDIM, BDIM, BDIM, BDIM, BDIM / 128);

  // ---- LN3: YN(bf16) = ln(F3O) ----  (YN aliases ATT, dead now)
  lnb_kernel<<<M3, 256, 0, stream>>>(F3O, ln3_g, ln3_b, YN);

  // ---- MLP, 2 row-chunks of 32768 ----
  for (int c = 0; c < 2; c++) {
    const bf16* Yc = YN + (size_t)c * MC * BDIM;
    const bf16* Fc = F3O + (size_t)c * MC * BDIM;
    float* outc = out + (size_t)c * MC * BDIM;
    gemm_kernel<1><<<(NMLP / 128) * (MC / 128), 512, 65536, stream>>>(
        Yc, W1t, b1, nullptr, H1, BDIM, BDIM, BDIM, NMLP, NMLP / 128);
    gemm_kernel<4><<<(BDIM / 128) * (MC / 128), 512, 65536, stream>>>(
        H1, W2t, b2, Fc, outc, NMLP, NMLP, NMLP, BDIM, BDIM / 128);
  }
}

// Round 9
// 773.101 us; speedup vs baseline: 1.5656x; 1.1334x over previous
//
#include <hip/hip_runtime.h>
#include <hip/hip_bf16.h>

typedef __attribute__((ext_vector_type(8))) short short8v;
typedef __attribute__((ext_vector_type(4))) float f32x4;
typedef __hip_bfloat16 bf16;

#define BDIM 512
#define NHEADS 8
#define DK 64
#define NBATCH 256
#define NN3 256
#define NN4 64
#define NMLP 2048

#define GLOAD_LDS16(g, l)                                                  \
  __builtin_amdgcn_global_load_lds(                                        \
      (const __attribute__((address_space(1))) void*)(g),                  \
      (__attribute__((address_space(3))) void*)(l), 16, 0, 0)

__device__ __forceinline__ float bf2f(short s) {
  union { short u[2]; float f; } cv;
  cv.u[0] = 0; cv.u[1] = s;
  return cv.f;
}
__device__ __forceinline__ short f2bf(float x) {
  bf16 h = __float2bfloat16(x);
  return *reinterpret_cast<short*>(&h);
}

// ---------------- weight convert: Wt[n][k] = bf16(W[k][n]) ----------------
__global__ __launch_bounds__(256) void convert_wt_kernel(
    const float* __restrict__ W, bf16* __restrict__ Wt, int K, int N) {
  int idx = blockIdx.x * 256 + threadIdx.x;
  if (idx >= K * N) return;
  int n = idx / K;
  int k = idx - n * K;
  Wt[idx] = __float2bfloat16(W[(size_t)k * N + n]);
}

// ------- wave-per-row LayerNorm (f32 in), +pos, optional extra outs -------
// 4 waves/block = 4 rows/block. Lane owns 8 consecutive f32 (2x float4).
__global__ __launch_bounds__(256) void ln_kernel(
    const float* __restrict__ x, const float* __restrict__ g,
    const float* __restrict__ beta, const float* __restrict__ pos, int nmod,
    bf16* __restrict__ out1, bf16* __restrict__ out2, bf16* __restrict__ raw) {
  int w = threadIdx.x >> 6, lane = threadIdx.x & 63;
  int row = blockIdx.x * 4 + w;
  int c0 = lane * 8;
  const float* xr = x + (size_t)row * BDIM + c0;
  float4 v0 = *(const float4*)xr;
  float4 v1 = *(const float4*)(xr + 4);
  float f[8] = {v0.x, v0.y, v0.z, v0.w, v1.x, v1.y, v1.z, v1.w};
  float s = 0.f, sq = 0.f;
#pragma unroll
  for (int i = 0; i < 8; i++) {
    s += f[i];
    sq += f[i] * f[i];
  }
#pragma unroll
  for (int o = 1; o <= 32; o <<= 1) {
    s += __shfl_xor(s, o);
    sq += __shfl_xor(sq, o);
  }
  float mean = s * (1.f / BDIM);
  float var = sq * (1.f / BDIM) - mean * mean;
  float rstd = rsqrtf(var + 1e-5f);
  float4 g0 = *(const float4*)(g + c0);
  float4 g1 = *(const float4*)(g + c0 + 4);
  float4 b0 = *(const float4*)(beta + c0);
  float4 b1 = *(const float4*)(beta + c0 + 4);
  float gg[8] = {g0.x, g0.y, g0.z, g0.w, g1.x, g1.y, g1.z, g1.w};
  float bb[8] = {b0.x, b0.y, b0.z, b0.w, b1.x, b1.y, b1.z, b1.w};
  float pv[8] = {};
  if (pos) {
    int n = row % nmod;
    const float* pr = pos + (size_t)n * BDIM + c0;
    float4 p0 = *(const float4*)pr;
    float4 p1 = *(const float4*)(pr + 4);
    pv[0] = p0.x; pv[1] = p0.y; pv[2] = p0.z; pv[3] = p0.w;
    pv[4] = p1.x; pv[5] = p1.y; pv[6] = p1.z; pv[7] = p1.w;
  }
  short8v o1, o2, rw;
#pragma unroll
  for (int i = 0; i < 8; i++) {
    float nv = (f[i] - mean) * rstd * gg[i] + bb[i];
    o1[i] = f2bf(nv + pv[i]);
    o2[i] = f2bf(nv);
    rw[i] = f2bf(f[i]);
  }
  size_t ob = (size_t)row * BDIM + c0;
  *(short8v*)(out1 + ob) = o1;
  if (out2) *(short8v*)(out2 + ob) = o2;
  if (raw) *(short8v*)(raw + ob) = rw;
}

// ---------- wave-per-row LayerNorm (bf16 in, bf16 out) --------------------
__global__ __launch_bounds__(256) void lnb_kernel(
    const bf16* __restrict__ x, const float* __restrict__ g,
    const float* __restrict__ beta, bf16* __restrict__ out) {
  int w = threadIdx.x >> 6, lane = threadIdx.x & 63;
  int row = blockIdx.x * 4 + w;
  int c0 = lane * 8;
  short8v v = *(const short8v*)(x + (size_t)row * BDIM + c0);
  float f[8];
  float s = 0.f, sq = 0.f;
#pragma unroll
  for (int i = 0; i < 8; i++) {
    f[i] = bf2f(v[i]);
    s += f[i];
    sq += f[i] * f[i];
  }
#pragma unroll
  for (int o = 1; o <= 32; o <<= 1) {
    s += __shfl_xor(s, o);
    sq += __shfl_xor(sq, o);
  }
  float mean = s * (1.f / BDIM);
  float var = sq * (1.f / BDIM) - mean * mean;
  float rstd = rsqrtf(var + 1e-5f);
  float4 g0 = *(const float4*)(g + c0);
  float4 g1 = *(const float4*)(g + c0 + 4);
  float4 b0 = *(const float4*)(beta + c0);
  float4 b1 = *(const float4*)(beta + c0 + 4);
  float gg[8] = {g0.x, g0.y, g0.z, g0.w, g1.x, g1.y, g1.z, g1.w};
  float bb[8] = {b0.x, b0.y, b0.z, b0.w, b1.x, b1.y, b1.z, b1.w};
  short8v o1;
#pragma unroll
  for (int i = 0; i < 8; i++) o1[i] = f2bf((f[i] - mean) * rstd * gg[i] + bb[i]);
  *(short8v*)(out + (size_t)row * BDIM + c0) = o1;
}

// ---------------- pipelined MFMA GEMM: out[M,N] = X[M,K] @ Wt[N,K]^T ------
// 128x128 tile, 8 waves (2x4), BK=64, 2 LDS buffers (64KB -> 2 blocks/CU),
// counted-vmcnt depth-2 prefetch, 2 raw barriers per K-step.
// EPI 0: bf16 out = acc + bias
// EPI 1: bf16 out = gelu(acc + bias)
// EPI 3: bf16 out = srcbf16[o] + acc + bias
// EPI 4: f32  out = srcbf16[o] + acc + bias
template <int EPI>
__global__ __launch_bounds__(512) void gemm_kernel(
    const bf16* __restrict__ X, const bf16* __restrict__ Wt,
    const float* __restrict__ bias, const void* __restrict__ src, void* outp,
    int K, int ldx, int ldw, int N, int gridX) {
  extern __shared__ bf16 lds[];  // 2 x 16384 elements (A 8192 + B 8192) = 64KB

  // XCD-aware bijective swizzle (nwg % 8 == 0 for all launches)
  int nwg = gridDim.x;
  int cpx = nwg >> 3;
  int bid = blockIdx.x;
  int nb = (bid & 7) * cpx + (bid >> 3);
  int bx = nb % gridX, by = nb / gridX;
  int row0 = by * 128, col0 = bx * 128;

  int t = threadIdx.x, w = t >> 6, lane = t & 63;
  int wr = w >> 2, wc = w & 3;           // 2 row-groups x 4 col-groups
  int r16 = lane & 15, kg = lane >> 4;
  int srow = lane >> 3;                   // 0..7
  int scol = ((lane & 7) ^ srow) * 8;     // inverse-swizzled source col (elems)

  // wave w stages A rows [w*16, w*16+16) and B rows [w*16, w*16+16)
  const bf16* gA0 = X + (size_t)(row0 + w * 16 + srow) * ldx + scol;
  const bf16* gB0 = Wt + (size_t)(col0 + w * 16 + srow) * ldw + scol;

  f32x4 acc[4][2] = {};

  auto stage = [&](int kt, int buf) {
    bf16* base = lds + buf * 16384;
    int ke = kt << 6;
#pragma unroll
    for (int j = 0; j < 2; j++) {
      GLOAD_LDS16(gA0 + ke + (size_t)j * 8 * ldx, base + (w * 16 + j * 8) * 64);
      GLOAD_LDS16(gB0 + ke + (size_t)j * 8 * ldw,
                  base + 8192 + (w * 16 + j * 8) * 64);
    }
  };

  auto compute = [&](int buf) {
    const char* base = (const char*)(lds + buf * 16384);
#pragma unroll
    for (int ksub = 0; ksub < 2; ksub++) {
      int cc = (ksub * 64 + kg * 16) ^ ((r16 & 7) << 4);
      short8v a[4], b[2];
#pragma unroll
      for (int m = 0; m < 4; m++)
        a[m] = *(const short8v*)(base + (wr * 64 + m * 16 + r16) * 128 + cc);
#pragma unroll
      for (int n = 0; n < 2; n++)
        b[n] = *(const short8v*)(base + 16384 + (wc * 32 + n * 16 + r16) * 128 + cc);
#pragma unroll
      for (int m = 0; m < 4; m++)
#pragma unroll
        for (int n = 0; n < 2; n++)
          acc[m][n] =
              __builtin_amdgcn_mfma_f32_16x16x32_bf16(a[m], b[n], acc[m][n], 0, 0, 0);
    }
  };

  int NT = K >> 6;
  stage(0, 0);
  stage(1, 1);
  for (int tt = 0; tt < NT; tt++) {
    // tile tt landed (4 loads/wave/tile; tile tt+1's 4 may stay in flight)
    if (tt < NT - 1)
      asm volatile("s_waitcnt vmcnt(4)" ::: "memory");
    else
      asm volatile("s_waitcnt vmcnt(0)" ::: "memory");
    __builtin_amdgcn_s_barrier();        // all waves' tile-tt loads visible
    asm volatile("" ::: "memory");
    compute(tt & 1);
    asm volatile("" ::: "memory");
    __builtin_amdgcn_s_barrier();        // all waves done reading buf tt&1
    asm volatile("" ::: "memory");
    if (tt + 2 < NT) stage(tt + 2, tt & 1);  // overlaps compute(tt+1)
  }

#pragma unroll
  for (int n = 0; n < 2; n++) {
    int col = col0 + wc * 32 + n * 16 + r16;
    float bv = bias ? bias[col] : 0.f;
#pragma unroll
    for (int m = 0; m < 4; m++)
#pragma unroll
      for (int r = 0; r < 4; r++) {
        int row = row0 + wr * 64 + m * 16 + kg * 4 + r;
        size_t o = (size_t)row * N + col;
        float val = acc[m][n][r] + bv;
        if (EPI == 0) {
          ((bf16*)outp)[o] = __float2bfloat16(val);
        } else if (EPI == 1) {
          float gl = 0.5f * val * (1.f + erff(val * 0.70710678f));
          ((bf16*)outp)[o] = __float2bfloat16(gl);
        } else if (EPI == 3) {
          ((bf16*)outp)[o] = __float2bfloat16(bf2f(((const short*)src)[o]) + val);
        } else {
          ((float*)outp)[o] = bf2f(((const short*)src)[o]) + val;
        }
      }
  }
}

// ---- ctx: fused k-softmax (over positions) + ctxT[bh][vc][kc] einsum -----
__global__ __launch_bounds__(256) void ctx_kernel(
    const bf16* __restrict__ kproj, const bf16* __restrict__ vbuf,
    bf16* __restrict__ ctxT) {
  int bh = blockIdx.x;
  int b = bh >> 3, h = bh & 7;
  __shared__ bf16 lk[NN4][DK], lv[NN4][DK];
  int t = threadIdx.x;
#pragma unroll
  for (int i = 0; i < 16; i++) {
    int idx = i * 256 + t;
    int n = idx >> 6, c = idx & 63;
    size_t gaddr = (size_t)b * NN4 * BDIM + (size_t)n * BDIM + h * DK + c;
    lk[n][c] = kproj[gaddr];
    lv[n][c] = vbuf[gaddr];
  }
  __syncthreads();
  if (t < 64) {
    int c = t;
    float e[NN4];
    float m = -1e30f;
#pragma unroll
    for (int n = 0; n < NN4; n++) {
      e[n] = bf2f(*(short*)&lk[n][c]);
      m = fmaxf(m, e[n]);
    }
    float s = 0.f;
#pragma unroll
    for (int n = 0; n < NN4; n++) {
      e[n] = __expf(e[n] - m);
      s += e[n];
    }
    float inv = 1.f / s;
#pragma unroll
    for (int n = 0; n < NN4; n++) lk[n][c] = __float2bfloat16(e[n] * inv);
  }
  __syncthreads();
  int vc = t >> 2;
  int kc0 = (t & 3) * 16;
  float acc[16] = {};
  for (int n = 0; n < NN4; n++) {
    float vv = __bfloat162float(lv[n][vc]);
#pragma unroll
    for (int i = 0; i < 16; i++)
      acc[i] += vv * __bfloat162float(lk[n][kc0 + i]);
  }
  size_t o = (size_t)bh * 4096 + (size_t)vc * 64 + kc0;
#pragma unroll
  for (int i = 0; i < 16; i++) ctxT[o + i] = __float2bfloat16(acc[i]);
}

// ---- att: fused q-softmax (in-register, over 64 head channels) + GEMM ----
__global__ __launch_bounds__(256) void att_kernel(
    const bf16* __restrict__ qproj, const bf16* __restrict__ ctxT,
    bf16* __restrict__ att) {
  int bh = blockIdx.x;
  int b = bh >> 3, h = bh & 7;
  int t = threadIdx.x, w = t >> 6, lane = t & 63;
  int r16 = lane & 15, kg = lane >> 4;
  f32x4 acc[4][4] = {};
  const bf16* qb = qproj + (size_t)b * NN3 * BDIM + h * DK;
  const bf16* cb = ctxT + (size_t)bh * 4096;
  short8v bb[2][4];
#pragma unroll
  for (int kt = 0; kt < 2; kt++)
#pragma unroll
    for (int ni = 0; ni < 4; ni++)
      bb[kt][ni] = *(const short8v*)(cb + (ni * 16 + r16) * 64 + kt * 32 + kg * 8);
#pragma unroll
  for (int mi = 0; mi < 4; mi++) {
    int rrow = w * 64 + mi * 16 + r16;
    short8v a0 = *(const short8v*)(qb + (size_t)rrow * BDIM + kg * 8);
    short8v a1 = *(const short8v*)(qb + (size_t)rrow * BDIM + 32 + kg * 8);
    float f[16];
#pragma unroll
    for (int i = 0; i < 8; i++) {
      f[i] = bf2f(a0[i]);
      f[8 + i] = bf2f(a1[i]);
    }
    float m = f[0];
#pragma unroll
    for (int i = 1; i < 16; i++) m = fmaxf(m, f[i]);
    m = fmaxf(m, __shfl_xor(m, 16));
    m = fmaxf(m, __shfl_xor(m, 32));
    float s = 0.f;
#pragma unroll
    for (int i = 0; i < 16; i++) {
      f[i] = __expf(f[i] - m);
      s += f[i];
    }
    s += __shfl_xor(s, 16);
    s += __shfl_xor(s, 32);
    float inv = 1.f / s;
    short8v A0, A1;
#pragma unroll
    for (int i = 0; i < 8; i++) {
      A0[i] = f2bf(f[i] * inv);
      A1[i] = f2bf(f[8 + i] * inv);
    }
#pragma unroll
    for (int ni = 0; ni < 4; ni++) {
      acc[mi][ni] = __builtin_amdgcn_mfma_f32_16x16x32_bf16(A0, bb[0][ni], acc[mi][ni], 0, 0, 0);
      acc[mi][ni] = __builtin_amdgcn_mfma_f32_16x16x32_bf16(A1, bb[1][ni], acc[mi][ni], 0, 0, 0);
    }
  }
#pragma unroll
  for (int mi = 0; mi < 4; mi++)
#pragma unroll
    for (int ni = 0; ni < 4; ni++)
#pragma unroll
      for (int r = 0; r < 4; r++) {
        int row = w * 64 + mi * 16 + kg * 4 + r;
        int col = ni * 16 + r16;
        att[(size_t)(b * NN3 + row) * BDIM + h * DK + col] =
            __float2bfloat16(acc[mi][ni][r]);
      }
}

extern "C" void kernel_launch(void* const* d_in, const int* in_sizes, int n_in,
                              void* d_out, int out_size, void* d_ws, size_t ws_size,
                              hipStream_t stream) {
  const float* f3 = (const float*)d_in[0];
  const float* f4 = (const float*)d_in[1];
  const float* pos3 = (const float*)d_in[2];
  const float* pos4 = (const float*)d_in[3];
  const float* ln1_g = (const float*)d_in[4];
  const float* ln1_b = (const float*)d_in[5];
  const float* ln2_g = (const float*)d_in[6];
  const float* ln2_b = (const float*)d_in[7];
  const float* ln3_g = (const float*)d_in[8];
  const float* ln3_b = (const float*)d_in[9];
  const float* Wq = (const float*)d_in[10];
  const float* bq = (const float*)d_in[11];
  const float* Wk = (const float*)d_in[12];
  const float* bk = (const float*)d_in[13];
  const float* Wv = (const float*)d_in[14];
  const float* bv = (const float*)d_in[15];
  const float* Wr = (const float*)d_in[16];
  const float* br = (const float*)d_in[17];
  const float* W1 = (const float*)d_in[18];
  const float* b1 = (const float*)d_in[19];
  const float* W2 = (const float*)d_in[20];
  const float* b2 = (const float*)d_in[21];
  float* out = (float*)d_out;

  const int M3 = NBATCH * NN3;  // 65536
  const int M4 = NBATCH * NN4;  // 16384
  const int MC = M3 / 2;        // 32768 MLP row-chunk

  char* ws = (char*)d_ws;
  size_t off = 0;
  auto alloc = [&](size_t bytes) {
    size_t r = off;
    off = (off + bytes + 255) & ~(size_t)255;
    return r;
  };
  size_t oWqt = alloc((size_t)BDIM * BDIM * 2);
  size_t oWkt = alloc((size_t)BDIM * BDIM * 2);
  size_t oWvt = alloc((size_t)BDIM * BDIM * 2);
  size_t oWrt = alloc((size_t)BDIM * BDIM * 2);
  size_t oW1t = alloc((size_t)BDIM * NMLP * 2);
  size_t oW2t = alloc((size_t)BDIM * NMLP * 2);
  size_t oXQ = alloc((size_t)M3 * BDIM * 2);  // ln(f3)+pos3 -> att -> Yn
  size_t oXK = alloc((size_t)M4 * BDIM * 2);
  size_t oXV = alloc((size_t)M4 * BDIM * 2);
  size_t oQF = alloc((size_t)M3 * BDIM * 2);  // q proj -> F3O
  size_t oKF = alloc((size_t)M4 * BDIM * 2);
  size_t oVF = alloc((size_t)M4 * BDIM * 2);
  size_t oF3B = alloc((size_t)M3 * BDIM * 2);  // bf16 copy of f3
  size_t oCT = alloc((size_t)NBATCH * NHEADS * DK * DK * 2);
  size_t oH1 = alloc((size_t)MC * NMLP * 2);  // 128MB hidden row-chunk
  (void)ws_size;

  bf16* Wqt = (bf16*)(ws + oWqt);
  bf16* Wkt = (bf16*)(ws + oWkt);
  bf16* Wvt = (bf16*)(ws + oWvt);
  bf16* Wrt = (bf16*)(ws + oWrt);
  bf16* W1t = (bf16*)(ws + oW1t);
  bf16* W2t = (bf16*)(ws + oW2t);
  bf16* XQ = (bf16*)(ws + oXQ);
  bf16* XK = (bf16*)(ws + oXK);
  bf16* XV = (bf16*)(ws + oXV);
  bf16* QF = (bf16*)(ws + oQF);
  bf16* KF = (bf16*)(ws + oKF);
  bf16* VF = (bf16*)(ws + oVF);
  bf16* F3B = (bf16*)(ws + oF3B);
  bf16* CT = (bf16*)(ws + oCT);
  bf16* H1 = (bf16*)(ws + oH1);
  bf16* ATT = XQ;   // reuse (XQ dead after q projection)
  bf16* F3O = QF;   // reuse (QF dead after att)
  bf16* YN = XQ;    // reuse (ATT dead after outproj)

  // dynamic-LDS cap for the 64KB GEMM
  hipFuncSetAttribute((const void*)gemm_kernel<0>,
                      hipFuncAttributeMaxDynamicSharedMemorySize, 65536);
  hipFuncSetAttribute((const void*)gemm_kernel<1>,
                      hipFuncAttributeMaxDynamicSharedMemorySize, 65536);
  hipFuncSetAttribute((const void*)gemm_kernel<3>,
                      hipFuncAttributeMaxDynamicSharedMemorySize, 65536);
  hipFuncSetAttribute((const void*)gemm_kernel<4>,
                      hipFuncAttributeMaxDynamicSharedMemorySize, 65536);

  // ---- weight conversion ----
  convert_wt_kernel<<<(BDIM * BDIM + 255) / 256, 256, 0, stream>>>(Wq, Wqt, BDIM, BDIM);
  convert_wt_kernel<<<(BDIM * BDIM + 255) / 256, 256, 0, stream>>>(Wk, Wkt, BDIM, BDIM);
  convert_wt_kernel<<<(BDIM * BDIM + 255) / 256, 256, 0, stream>>>(Wv, Wvt, BDIM, BDIM);
  convert_wt_kernel<<<(BDIM * BDIM + 255) / 256, 256, 0, stream>>>(Wr, Wrt, BDIM, BDIM);
  convert_wt_kernel<<<(BDIM * NMLP + 255) / 256, 256, 0, stream>>>(W1, W1t, BDIM, NMLP);
  convert_wt_kernel<<<(BDIM * NMLP + 255) / 256, 256, 0, stream>>>(W2, W2t, NMLP, BDIM);

  // ---- layernorms (f3 pass also emits bf16 raw copy for residual) ----
  ln_kernel<<<M3 / 4, 256, 0, stream>>>(f3, ln1_g, ln1_b, pos3, NN3, XQ, nullptr, F3B);
  ln_kernel<<<M4 / 4, 256, 0, stream>>>(f4, ln2_g, ln2_b, pos4, NN4, XK, XV, nullptr);

  // ---- projections ----
  gemm_kernel<0><<<(BDIM / 128) * (M3 / 128), 512, 65536, stream>>>(
      XQ, Wqt, bq, nullptr, QF, BDIM, BDIM, BDIM, BDIM, BDIM / 128);
  gemm_kernel<0><<<(BDIM / 128) * (M4 / 128), 512, 65536, stream>>>(
      XK, Wkt, bk, nullptr, KF, BDIM, BDIM, BDIM, BDIM, BDIM / 128);
  gemm_kernel<0><<<(BDIM / 128) * (M4 / 128), 512, 65536, stream>>>(
      XV, Wvt, bv, nullptr, VF, BDIM, BDIM, BDIM, BDIM, BDIM / 128);

  // ---- context (fused k-softmax) + att (fused q-softmax) ----
  ctx_kernel<<<NBATCH * NHEADS, 256, 0, stream>>>(KF, VF, CT);
  att_kernel<<<NBATCH * NHEADS, 256, 0, stream>>>(QF, CT, ATT);

  // ---- output projection: F3O(bf16) = f3(bf16 copy) + att @ Wr + br ----
  gemm_kernel<3><<<(BDIM / 128) * (M3 / 128), 512, 65536, stream>>>(
      ATT, Wrt, br, F3B, F3O, BDIM, BDIM, BDIM, BDIM, BDIM / 128);

  // ---- LN3: YN(bf16) = ln(F3O) ----  (YN aliases ATT, dead now)
  lnb_kernel<<<M3 / 4, 256, 0, stream>>>(F3O, ln3_g, ln3_b, YN);

  // ---- MLP, 2 row-chunks of 32768 ----
  for (int c = 0; c < 2; c++) {
    const bf16* Yc = YN + (size_t)c * MC * BDIM;
    const bf16* Fc = F3O + (size_t)c * MC * BDIM;
    float* outc = out + (size_t)c * MC * BDIM;
    gemm_kernel<1><<<(NMLP / 128) * (MC / 128), 512, 65536, stream>>>(
        Yc, W1t, b1, nullptr, H1, BDIM, BDIM, BDIM, NMLP, NMLP / 128);
    gemm_kernel<4><<<(BDIM / 128) * (MC / 128), 512, 65536, stream>>>(
        H1, W2t, b2, Fc, outc, NMLP, NMLP, NMLP, BDIM, BDIM / 128);
  }
}